// Round 2
// baseline (129.666 us; speedup 1.0000x reference)
//
#include <hip/hip_runtime.h>

// LrDistance: out[s,m,n] = invalid ? 100 : |lr[s,m,n] + bilinear(rl[s], gx, gy)|
// grid_sample: padding_mode='zeros', align_corners=False.
//
// R9: barrier-free per-wave windows.
//   Element n gathers only from blended-row cols [n-66, n+1] (d in [0,64)).
//   => a wave's 256 output cols need a 323-float window: NO cross-wave
//   sharing. Each wave owns a private double-buffered 512-float LDS window
//   (used idx range [62,385]); loads, blends, gathers with zero
//   __syncthreads. 32 independent waves/CU free-run their pipelines --
//   no barrier-drain of in-flight prefetch (the R8 residual).
//   - rl row reuse kept: within 6-aligned groups y0(m+1)==y1(m) (crossover
//     at m=384 is 6-aligned), so next row's window-A is current window-B.
//   - Per-element math bit-identical to validated R7/R8 (absmax 0.25):
//     ix = fmaf(-d, C1, bx), ds_read2 pair gather, zero-folded y weights.
//   - Window global loads clamped to [0, N-4] (clamped slots land at unused
//     LDS idx; col>=1024 values are don't-care: x1in forces b=0 there).

constexpr int S = 16;
constexpr int M = 768;
constexpr int N = 1024;
constexpr int ROWS = 6;            // rows per block; 768 % 6 == 0, 384 % 6 == 0
constexpr int BPI = M / ROWS;      // blocks per image = 128
constexpr int WSZ = 512;           // per-wave window floats (used: [62,385])

typedef float vfloat4 __attribute__((ext_vector_type(4)));

__global__ __launch_bounds__(256, 8) void lr_distance_kernel(
    const float* __restrict__ lr,
    const float* __restrict__ rl,
    float* __restrict__ out)
{
    __shared__ float br[2][4][WSZ];   // [buf][wave][window]; 16 KB/block

    const int blk  = blockIdx.x;
    const int s    = blk / BPI;
    const int m0   = (blk - s * BPI) * ROWS;
    const int tid  = threadIdx.x;
    const int wq   = tid >> 6;        // wave id: owns cols [wq*256, wq*256+256)
    const int lane = tid & 63;

    const float* rlp = rl + (size_t)s * M * N;

    const int wstart = wq * 256 - 128;            // window global col start
    const int n0     = wq * 256 + lane * 4;
    // clamped, float4-aligned window load cols (clamped slots are unused idx)
    const int c0 = min(max(wstart + lane * 4, 0), N - 4);
    const int c1 = min(max(wstart + 256 + lane * 4, 0), N - 4);

    // --- per-row y interpolation params (wave-uniform, reference op order) ---
    auto yrow = [&](int m, float& w0z, float& w1z, int& y0c, int& y1c) {
        const float gy  = (2.0f * (float)m) / (float)(M - 1) - 1.0f;
        const float iy  = ((gy + 1.0f) * (float)M - 1.0f) * 0.5f;
        const float y0f = floorf(iy);
        const float y1f = y0f + 1.0f;
        const float wy1 = iy - y0f;
        const float wy0 = 1.0f - wy1;
        const bool  y0in = (y0f >= 0.0f) && (y0f <= (float)(M - 1));
        const bool  y1in = (y1f >= 0.0f) && (y1f <= (float)(M - 1));
        w0z = y0in ? wy0 : 0.0f;        // zeros-padding folded into weight
        w1z = y1in ? wy1 : 0.0f;
        y0c = min(max((int)y0f, 0), M - 1);
        y1c = min(max((int)y1f, 0), M - 1);
    };

    constexpr float C1 = 1024.0f / 1023.0f;
    const float fn0 = (float)n0;                  // exact (int < 2^24)
    const float bx0 = fmaf(fn0, C1, -0.5f);       // ix base for k=0

    // --- prologue: row m0 needs both rl windows; later rows reuse B -> A ---
    float w0z, w1z; int y0c, y1c;
    yrow(m0, w0z, w1z, y0c, y1c);
    const float* rp0 = rlp + (size_t)y0c * N;
    const float* rp1 = rlp + (size_t)y1c * N;
    vfloat4 rA0 = *reinterpret_cast<const vfloat4*>(rp0 + c0);
    vfloat4 rA1 = *reinterpret_cast<const vfloat4*>(rp0 + c1);
    vfloat4 rB0 = *reinterpret_cast<const vfloat4*>(rp1 + c0);
    vfloat4 rB1 = *reinterpret_cast<const vfloat4*>(rp1 + c1);
    size_t base = (size_t)(s * M + m0) * N + n0;
    vfloat4 d4 = __builtin_nontemporal_load(
        reinterpret_cast<const vfloat4*>(lr + base));

    float* const wb0 = &br[0][wq][0];
    float* const wb1 = &br[1][wq][0];

#pragma unroll 2
    for (int i = 0; i < ROWS; ++i) {
        float* const wb = (i & 1) ? wb1 : wb0;

        // --- prefetch next row (issue first; overlaps everything below) ---
        vfloat4 nB0 = {}, nB1 = {}, nd = {};
        float nw0z = 0.0f, nw1z = 0.0f; int ny0c = 0, ny1c = 0;
        if (i + 1 < ROWS) {
            yrow(m0 + i + 1, nw0z, nw1z, ny0c, ny1c);
            // within the group: y0(m+1) == y1(m) -> next A-window is current B
            const float* rp = rlp + (size_t)ny1c * N;
            nB0 = *reinterpret_cast<const vfloat4*>(rp + c0);
            nB1 = *reinterpret_cast<const vfloat4*>(rp + c1);
            nd  = __builtin_nontemporal_load(
                reinterpret_cast<const vfloat4*>(lr + base + N));
        }

        // --- blend + stage private window (no barrier: wave-private region) ---
        *reinterpret_cast<vfloat4*>(wb + lane * 4)       = w0z * rA0 + w1z * rB0;
        *reinterpret_cast<vfloat4*>(wb + 256 + lane * 4) = w0z * rA1 + w1z * rB1;

        // --- gather + compute current row ---
        const float dv[4] = {d4.x, d4.y, d4.z, d4.w};
        float ov[4];
#pragma unroll
        for (int k = 0; k < 4; ++k) {
            const float d   = dv[k];
            const float fnk = fn0 + (float)k;          // exact
            const float xr  = fnk - d;                 // bit-exact predicate input
            const float bxk = bx0 + (float)k * C1;
            const float ix  = fmaf(-d, C1, bxk);       // = xr*C1 - 0.5 (±1-2 ulp)
            const float x0f = floorf(ix);
            const float wx1 = ix - x0f;
            const int   x0  = (int)x0f;                // in [n-66, n]
            const int   xb  = max(x0, 0);              // pair base
            const int   idx = xb - wstart;             // in [62, 384]

            const float p0 = wb[idx];
            const float p1 = wb[idx + 1];              // ds_read2_b32 with p0

            const bool  x0in = (x0 >= 0);
            const bool  x1in = (x0 <= N - 2);
            const float a  = x0in ? p0 : 0.0f;
            float       b  = x0in ? p1 : p0;           // x0=-1 -> x1=0 -> p0
            b = x1in ? b : 0.0f;

            const float warped = fmaf(wx1, b - a, a);  // = wx0*a + wx1*b
            ov[k] = (xr >= 0.0f) ? fabsf(d + warped) : 100.0f;  // xr < N always
        }

        vfloat4 o4;
        o4.x = ov[0]; o4.y = ov[1]; o4.z = ov[2]; o4.w = ov[3];
        __builtin_nontemporal_store(o4, reinterpret_cast<vfloat4*>(out + base));

        // --- rotate pipeline state ---
        rA0 = rB0; rA1 = rB1; rB0 = nB0; rB1 = nB1; d4 = nd;
        w0z = nw0z; w1z = nw1z; y0c = ny0c; y1c = ny1c;
        base += N;
    }
}

extern "C" void kernel_launch(void* const* d_in, const int* in_sizes, int n_in,
                              void* d_out, int out_size, void* d_ws, size_t ws_size,
                              hipStream_t stream) {
    const float* lr  = (const float*)d_in[0];   // disps_lr [16,1,768,1024] fp32
    const float* rl  = (const float*)d_in[1];   // disps_rl [16,1,768,1024] fp32
    float*       out = (float*)d_out;

    const int blocks  = (S * M) / ROWS;  // 2048 blocks = exactly 8/CU resident
    const int threads = 256;             // 4 waves, each owning a quarter-row

    lr_distance_kernel<<<blocks, threads, 0, stream>>>(lr, rl, out);
}

// Round 8
// 129.584 us; speedup vs baseline: 1.0006x; 1.0006x over previous
//
#include <hip/hip_runtime.h>

// LrDistance: out[s,m,n] = invalid ? 100 : |lr[s,m,n] + bilinear(rl[s], gx, gy)|
// grid_sample: padding_mode='zeros', align_corners=False.
//
// R15 = R14 resubmitted verbatim (R14's bench was an infra failure --
// "container failed twice" -- not a kernel verdict; the kernel cannot hang:
// no barriers, no data-dependent loops, all waits satisfiable, all addresses
// in-bounds and aligned).
//
// R14: direct global->LDS windows using ONLY the measured width-16 path.
//   R10-R13 all used __builtin_amdgcn_global_load_lds(..., 12, ...). Width 12
//   is NOT hardware-verified (guide: 4 [m03] and 16 [m97] measured; 12 has no
//   tag). If hipcc legalizes 12B into multiple VMEM ops (3x dword), every
//   window issue is 6 vmcnt events instead of 2 and ALL ledgers undercount ->
//   half-written windows at every gather -> the persistent garbage signature
//   (4009/496/840) that survived three independent order/count fixes.
//   This version: 512-float windows = 64 lanes x 8 floats = exactly 2x
//   global_load_lds_dwordx4 per window (the m97-measured instruction).
// Geometry:
//   wstart = wq*256 - 128 (uniform, == 0 mod 4 -> clamp stays slot-aligned
//   at BOTH edges with 4-float lane stride):
//     wq0: lane 32 of op1 starts exactly at col 0; left-clamped lanes write
//          slots<128 <-> cols<0, never read (idx = xb+128 >= 128).
//     wq3: lane 31 of op2 starts exactly at col 1020 (N-4); clamped lanes
//          32+ write slots <-> cols>=1024, read only under x1in=false.
//     wq1/wq2: no clamping (ranges [128,640)/[384,896) inside [0,1020]).
//   Gather: element n reads cols [n-66, n+1]; window [n0w-128, n0w+384)
//   covers it; idx = xb - wstart in [62, 384], idx+1 <= 385 < 512.
// Schedule (pinned with asm volatile("":::"memory") between issue groups):
//   W0ab W1ab | L0 | per-iter: L(i+1) | W(i+2)ab | wait | gather | S(i) |
//   Ledger (2 W-ops per window, in-order vmcnt retire, verified by induction):
//     i=0:    outstanding {W0ab W1ab L0 L1 W2ab}=8, need thru L0 -> vmcnt(3)
//     i=1..4: outstanding 8, newest 4 = {S(i-1) L(i+1) W(i+2)ab} -> vmcnt(4)
//     i=5:    outstanding {S3 L5 W6ab S4}=5, need thru W6b      -> vmcnt(1)
//   Never vmcnt(0): next-row prefetches stay in flight across every wait.
//   Ring WAR safety: W(j) (slot j%3) issued at iter j-2; window j-3 (same
//   slot) last read at iter j-3 < j-2 in wave program order.
// Structure: per-wave rotating 3-window ring, rows i,i+1 in use, i+2 in
//   flight; zero barriers, zero ds_writes, no VGPR staging; y-blend folded
//   into the gather; window rows consecutive within a 6-aligned group
//   (y0(m)=m-1 for m<=383, m for m>=384; crossover 384 is 6-aligned).
//   Per-element x math bit-identical to validated R7/R8/R9 (absmax 0.25).

constexpr int S = 16;
constexpr int M = 768;
constexpr int N = 1024;
constexpr int ROWS = 6;            // rows per block; 768 % 6 == 0, 384 % 6 == 0
constexpr int BPI = M / ROWS;      // blocks per image = 128
constexpr int WSZ = 512;           // per-wave window floats (2x dwordx4/lane)

typedef float vfloat4 __attribute__((ext_vector_type(4)));
typedef const float __attribute__((address_space(1))) gfloat;
typedef float __attribute__((address_space(3))) lfloat;

#define PIN() asm volatile("" ::: "memory")

__global__ __launch_bounds__(256, 8) void lr_distance_kernel(
    const float* __restrict__ lr,
    const float* __restrict__ rl,
    float* __restrict__ out)
{
    __shared__ float win[4][3][WSZ];   // [wave][ring][window]; 24 KB/block

    const int blk  = blockIdx.x;
    const int s    = blk / BPI;
    const int m0   = (blk - s * BPI) * ROWS;
    const int tid  = threadIdx.x;
    const int wq   = tid >> 6;            // wave id: owns cols [wq*256, +256)
    const int lane = tid & 63;

    const float* rlp = rl + (size_t)s * M * N;
    const int wstart = wq * 256 - 128;    // == 0 mod 4: clamp-slot-aligned
    const int n0     = wq * 256 + lane * 4;

    // clamped per-lane source cols for the two 16-byte gld_lds ops
    const int g0 = min(max(wstart + lane * 4, 0), N - 4);
    const int g1 = min(max(wstart + 256 + lane * 4, 0), N - 4);

    // window row sequence: w[j] = rl row clamp(r0m + j), r0m = y0(m0)
    const int r0m = (m0 <= 383) ? (m0 - 1) : m0;

    auto issueW = [&](int j) {
        const int row = min(max(r0m + j, 0), M - 1);
        const float* rp = rlp + (size_t)row * N;
        float* dst = &win[wq][j % 3][0];
        __builtin_amdgcn_global_load_lds((gfloat*)(rp + g0), (lfloat*)dst,
                                         16, 0, 0);
        __builtin_amdgcn_global_load_lds((gfloat*)(rp + g1), (lfloat*)(dst + 256),
                                         16, 0, 0);
    };

    constexpr float C1 = 1024.0f / 1023.0f;
    const float fn0 = (float)n0;                  // exact (int < 2^24)
    const float bx0 = fmaf(fn0, C1, -0.5f);       // ix base for k=0

    // --- prologue: windows 0,1 first, then first lr row; order pinned ---
    issueW(0);
    issueW(1);
    PIN();
    size_t base = (size_t)(s * M + m0) * N + n0;
    vfloat4 d4 = __builtin_nontemporal_load(
        reinterpret_cast<const vfloat4*>(lr + base));
    PIN();

#pragma unroll
    for (int i = 0; i < ROWS; ++i) {
        // --- issue next lr row, THEN next-next window (order pinned) ---
        vfloat4 nd = {};
        if (i + 1 < ROWS)
            nd = __builtin_nontemporal_load(
                reinterpret_cast<const vfloat4*>(lr + base + N));
        PIN();
        if (i + 2 <= ROWS) issueW(i + 2);   // windows 0..6: row i uses i, i+1

        // --- y-weights for row m0+i (wave-uniform, reference op order) ---
        const int m = m0 + i;
        const float gy  = (2.0f * (float)m) / (float)(M - 1) - 1.0f;
        const float iy  = ((gy + 1.0f) * (float)M - 1.0f) * 0.5f;
        const float y0f = floorf(iy);
        const float y1f = y0f + 1.0f;
        const float wy1 = iy - y0f;
        const float wy0 = 1.0f - wy1;
        const float w0z = (y0f >= 0.0f && y0f <= (float)(M - 1)) ? wy0 : 0.0f;
        const float w1z = (y1f >= 0.0f && y1f <= (float)(M - 1)) ? wy1 : 0.0f;

        // --- counted wait per ledger (see header); never vmcnt(0) ---
        if (i == 0)            asm volatile("s_waitcnt vmcnt(3)" ::: "memory");
        else if (i < ROWS - 1) asm volatile("s_waitcnt vmcnt(4)" ::: "memory");
        else                   asm volatile("s_waitcnt vmcnt(1)" ::: "memory");

        const float* wA = &win[wq][i % 3][0];        // y0 row window
        const float* wB = &win[wq][(i + 1) % 3][0];  // y1 row window

        // --- gather + blend + compute current row ---
        const float dv[4] = {d4.x, d4.y, d4.z, d4.w};
        float ov[4];
#pragma unroll
        for (int k = 0; k < 4; ++k) {
            const float d   = dv[k];
            const float fnk = fn0 + (float)k;          // exact
            const float xr  = fnk - d;                 // bit-exact predicate input
            const float bxk = bx0 + (float)k * C1;
            const float ix  = fmaf(-d, C1, bxk);       // = xr*C1 - 0.5 (+-1-2 ulp)
            const float x0f = floorf(ix);
            const float wx1 = ix - x0f;
            const int   x0  = (int)x0f;                // in [n-66, n]
            const int   xb  = max(x0, 0);              // pair base
            const int   idx = xb - wstart;             // in [62, 384]

            const float p0A = wA[idx];
            const float p1A = wA[idx + 1];             // ds_read2_b32 with p0A
            const float p0B = wB[idx];
            const float p1B = wB[idx + 1];             // ds_read2_b32 with p0B

            // y-blend at gather (same fma shapes as the staged blend)
            const float pa = fmaf(w1z, p0B, w0z * p0A);
            const float pb = fmaf(w1z, p1B, w0z * p1A);

            const bool  x0in = (x0 >= 0);
            const bool  x1in = (x0 <= N - 2);
            const float a  = x0in ? pa : 0.0f;
            float       b  = x0in ? pb : pa;           // x0=-1 -> x1=0 -> col0
            b = x1in ? b : 0.0f;

            const float warped = fmaf(wx1, b - a, a);  // = wx0*a + wx1*b
            ov[k] = (xr >= 0.0f) ? fabsf(d + warped) : 100.0f;  // xr < N always
        }

        vfloat4 o4;
        o4.x = ov[0]; o4.y = ov[1]; o4.z = ov[2]; o4.w = ov[3];
        __builtin_nontemporal_store(o4, reinterpret_cast<vfloat4*>(out + base));
        PIN();   // pin S(i) before next iteration's L/W issues

        base += N;
        d4 = nd;
    }
}

extern "C" void kernel_launch(void* const* d_in, const int* in_sizes, int n_in,
                              void* d_out, int out_size, void* d_ws, size_t ws_size,
                              hipStream_t stream) {
    const float* lr  = (const float*)d_in[0];   // disps_lr [16,1,768,1024] fp32
    const float* rl  = (const float*)d_in[1];   // disps_rl [16,1,768,1024] fp32
    float*       out = (float*)d_out;

    const int blocks  = (S * M) / ROWS;  // 2048 blocks = 8/CU resident
    const int threads = 256;             // 4 waves, each owning a quarter-row

    lr_distance_kernel<<<blocks, threads, 0, stream>>>(lr, rl, out);
}